// Round 5
// baseline (1612.963 us; speedup 1.0000x reference)
//
#include <hip/hip_runtime.h>
#include <math.h>

#define BB 32
#define TT 64
#define NNODES 256
#define FDIM 64
#define SLICE (NNODES*FDIM)          // 16384 floats per (b,t) slice
#define NTOT (BB*TT*NNODES*FDIM)     // 33554432
#define RANK0 838860u                // ascending order-statistic index: T*N*F - k - 1, k=209715

typedef float v2f __attribute__((ext_vector_type(2)));
__device__ __forceinline__ v2f pkfma(v2f a, v2f b, v2f c) {
#if __has_builtin(__builtin_elementwise_fma)
  return __builtin_elementwise_fma(a, b, c);   // -> v_pk_fma_f32
#else
  v2f r; r.x = fmaf(a.x,b.x,c.x); r.y = fmaf(a.y,b.y,c.y); return r;
#endif
}

// ---------------- weight combine: 7 effective taps (-3..+3) ----------------
__global__ __launch_bounds__(256) void combine_w(
    const float* __restrict__ Wc1, const float* __restrict__ bc1,
    const float* __restrict__ Wc2, const float* __restrict__ bc2,
    const float* __restrict__ Wc3, const float* __restrict__ bc3,
    float* __restrict__ Wcomb, float* __restrict__ bcomb)
{
  const int FF2 = FDIM*FDIM;
  int gid = blockIdx.x*256 + threadIdx.x;
  if (gid < 7*FF2) {
    int j = gid / FF2, r = gid % FF2;
    float v;
    switch (j) {
      case 0: v = Wc3[r]; break;                                   // offset -3
      case 1: v = Wc2[r]; break;                                   // offset -2
      case 2: v = Wc1[r]; break;                                   // offset -1
      case 3: v = Wc1[FF2+r] + Wc2[FF2+r] + Wc3[FF2+r]; break;     // offset  0
      case 4: v = Wc1[2*FF2+r]; break;                             // offset +1
      case 5: v = Wc2[2*FF2+r]; break;                             // offset +2
      default: v = Wc3[2*FF2+r]; break;                            // offset +3
    }
    Wcomb[gid] = v;
  }
  if (gid < FDIM) bcomb[gid] = bc1[gid] + bc2[gid] + bc3[gid];
}

// ---------------- fold Q/K projections: Wqk = Wq*Wk^T, zb = bq*Wk^T ----------------
// (the x·Wq·bk + bq·bk term is constant along m -> cancels in softmax exactly)
__global__ __launch_bounds__(256) void combine_qk(
    const float* __restrict__ Wq, const float* __restrict__ bq,
    const float* __restrict__ Wk,
    float* __restrict__ Wqk, float* __restrict__ zb)
{
  int gid = blockIdx.x*256 + threadIdx.x;
  if (gid < 4096) {
    int i = gid >> 6, j = gid & 63;
    float a = 0.f;
    for (int o=0;o<64;o++) a = fmaf(Wq[i*64+o], Wk[j*64+o], a);
    Wqk[i*64+j] = a;
  } else if (gid < 4160) {
    int j = gid - 4096;
    float a = 0.f;
    for (int o=0;o<64;o++) a = fmaf(bq[o], Wk[j*64+o], a);
    zb[j] = a;
  }
}

// ---------------- dilated conv block + residual, per (b,n) slice ----------------
__global__ __launch_bounds__(256,4) void conv_kernel(
    const float* __restrict__ x, const float* __restrict__ Wcomb,
    const float* __restrict__ bcomb, float* __restrict__ x1)
{
  __shared__ float xs[64*72];        // [f][t+4], t in [-4,68), zero-padded
  const int bn = blockIdx.x; const int b = bn >> 8; const int n = bn & 255;
  const int tid = threadIdx.x;
#pragma unroll
  for (int k=0;k<18;k++) xs[k*256+tid] = 0.f;
  __syncthreads();
  const float* xbase = x + ((size_t)b*TT)*SLICE + n*FDIM;
#pragma unroll
  for (int it=0; it<4; it++) {
    int flat4 = it*256 + tid;
    int t = flat4 >> 4, f4 = (flat4 & 15) << 2;
    float4 v = *(const float4*)(xbase + (size_t)t*SLICE + f4);
    xs[(f4+0)*72 + t+4] = v.x;
    xs[(f4+1)*72 + t+4] = v.y;
    xs[(f4+2)*72 + t+4] = v.z;
    xs[(f4+3)*72 + t+4] = v.w;
  }
  __syncthreads();
  const int o = tid & 63;            // lane -> output feature
  const int tb = (tid >> 6) << 4;    // wave -> 16-step t range (wave-uniform)
  float acc[16];
  const float bco = bcomb[o];
#pragma unroll
  for (int k=0;k<16;k++) acc[k] = bco;
  for (int i=0;i<FDIM;i++) {
    float xr[24];
#pragma unroll
    for (int q=0;q<6;q++) {          // aligned b128 broadcast reads (tb wave-uniform)
      float4 v = *(const float4*)&xs[i*72 + tb + q*4];
      xr[q*4+0]=v.x; xr[q*4+1]=v.y; xr[q*4+2]=v.z; xr[q*4+3]=v.w;
    }
#pragma unroll
    for (int j=0;j<7;j++) {
      float w = Wcomb[(j*FDIM+i)*FDIM + o];   // coalesced, L2-hot
#pragma unroll
      for (int k=0;k<16;k++) acc[k] = fmaf(xr[k+j+1], w, acc[k]);
    }
  }
  float* obase = x1 + ((size_t)b*TT)*SLICE + n*FDIM + o;
#pragma unroll
  for (int k=0;k<16;k++) {
    int t = tb + k;
    float c = acc[k];
    float outv = xs[o*72 + t+4] + (c > 0.f ? c : 0.f);  // residual + relu
    obase[(size_t)t*SLICE] = outv;
  }
}

// ---------------- attention (diag softmax) + dense + inf-norm, per (b,t) ----------------
// 512 threads; lanes l and l^32 of wave w share node n = ((w&3)<<6)|((w>>2)<<5)|(l&31).
// k-split across mates: lane-half g = l>>5 owns k in [32g,32g+32). z-half (32 floats)
// in 16 v2f VGPRs. Score sweep covers ALL 256 m with per-m partial dots; mates combine
// partials via shfl_xor(32), then split the exp work (g=0: m%8 in [0,4), g=1: rest).
// Keeps peak VGPR < 128 so __launch_bounds__(512,4) doesn't spill (R4 lesson).
__global__ __launch_bounds__(512,4) void attn_kernel(
    const float* __restrict__ x1,
    const float* __restrict__ Wqk, const float* __restrict__ zb,
    const float* __restrict__ Wv, const float* __restrict__ bv,
    const float* __restrict__ Wd, const float* __restrict__ bd,
    float* __restrict__ vout)
{
  __shared__ float ks[NNODES*68];    // x slice (stride 68), reused for output transpose
  const int bt = blockIdx.x;
  const int tid = threadIdx.x;
  const int w = tid >> 6, l = tid & 63;
  const int g = l >> 5;                         // k-half / o-half selector
  const int n = ((w & 3) << 6) | ((w >> 2) << 5) | (l & 31);
  const int col0 = 32 * g;
  const float* xsl = x1 + (size_t)bt*SLICE;

  const float4* xb4 = (const float4*)xsl;
#pragma unroll
  for (int it=0; it<8; it++) {       // coalesced stage-in (512 threads)
    int flat4 = it*512 + tid;
    int nn = flat4 >> 4, f4 = (flat4 & 15) << 2;
    *(float4*)&ks[nn*68 + f4] = xb4[flat4];
  }
  __syncthreads();

  // z-half = x[n]·Wqk[:,col0:col0+32] + zb[col0:+32], streamed from LDS
  v2f zp[16];
#pragma unroll
  for (int j=0;j<16;j++) { v2f t; t.x = zb[col0+2*j]; t.y = zb[col0+2*j+1]; zp[j] = t; }
  for (int q=0;q<16;q++) {
    float4 xc = *(const float4*)&ks[n*68 + 4*q];
    float xe[4] = {xc.x, xc.y, xc.z, xc.w};
#pragma unroll
    for (int e=0;e<4;e++) {
      int i = 4*q + e;
      v2f xv; xv.x = xe[e]; xv.y = xe[e];
      const float4* wr = (const float4*)(Wqk + i*64 + col0);
#pragma unroll
      for (int qq=0;qq<8;qq++) {
        float4 w4 = wr[qq];
        v2f wlo; wlo.x=w4.x; wlo.y=w4.y;
        v2f whi; whi.x=w4.z; whi.y=w4.w;
        zp[2*qq]   = pkfma(xv, wlo, zp[2*qq]);
        zp[2*qq+1] = pkfma(xv, whi, zp[2*qq+1]);
      }
    }
  }

  // score sweep over all 256 m (own k-half), 8-m tiles; mates exchange partials
  float S = 0.f, diag = 0.f;
  const int i0 = 4 * g;              // exp-work split within each 8-m tile
  for (int T=0; T<32; T++) {
    const int mr = 8*T;
    v2f acc[8];
#pragma unroll
    for (int i=0;i<8;i++) { acc[i].x = 0.f; acc[i].y = 0.f; }
#pragma unroll
    for (int kc=0; kc<8; kc++) {
      float4 xc[8];
#pragma unroll
      for (int i=0;i<8;i++) xc[i] = *(const float4*)&ks[(mr+i)*68 + col0 + 4*kc];
      v2f zlo = zp[2*kc], zhi = zp[2*kc+1];
#pragma unroll
      for (int i=0;i<8;i++) {
        v2f xlo; xlo.x=xc[i].x; xlo.y=xc[i].y;
        v2f xhi; xhi.x=xc[i].z; xhi.y=xc[i].w;
        acc[i] = pkfma(zlo, xlo, acc[i]);
        acc[i] = pkfma(zhi, xhi, acc[i]);
      }
    }
    float sh[8];
#pragma unroll
    for (int i=0;i<8;i++) sh[i] = acc[i].x + acc[i].y;
#pragma unroll
    for (int i=0;i<8;i++) {
      float so = __shfl_xor(sh[i], 32);        // mate's k-half partial
      sh[i] = (sh[i] + so) * 0.125f;           // full score, identical on both mates
    }
#pragma unroll
    for (int ii=0; ii<4; ii++) {
      int m = mr + i0 + ii;
      float s = sh[i0 + ii];
      if (m == n) diag = s;
      S += __expf(s);
    }
  }
  S    += __shfl_xor(S, 32);
  diag += __shfl_xor(diag, 32);      // non-capturing mate contributes 0
  const float ann = __expf(diag) / S;

  // V-projection (own o-half), streamed x; o1 = x + relu(ann*(xWv+bv))
  float o1own[32];
  {
    v2f vacc[16];
#pragma unroll
    for (int j=0;j<16;j++) { v2f t; t.x = bv[col0+2*j]; t.y = bv[col0+2*j+1]; vacc[j] = t; }
    for (int q=0;q<16;q++) {
      float4 xc = *(const float4*)&ks[n*68 + 4*q];
      float xe[4] = {xc.x, xc.y, xc.z, xc.w};
#pragma unroll
      for (int e=0;e<4;e++) {
        int i = 4*q + e;
        v2f xv; xv.x = xe[e]; xv.y = xe[e];
        const float4* wr = (const float4*)(Wv + i*64 + col0);
#pragma unroll
        for (int qq=0;qq<8;qq++) {
          float4 w4 = wr[qq];
          v2f wlo; wlo.x=w4.x; wlo.y=w4.y;
          v2f whi; whi.x=w4.z; whi.y=w4.w;
          vacc[2*qq]   = pkfma(xv, wlo, vacc[2*qq]);
          vacc[2*qq+1] = pkfma(xv, whi, vacc[2*qq+1]);
        }
      }
    }
#pragma unroll
    for (int q=0;q<8;q++) {          // own x half for residual
      float4 xc = *(const float4*)&ks[n*68 + col0 + 4*q];
      float xe[4] = {xc.x, xc.y, xc.z, xc.w};
#pragma unroll
      for (int e=0;e<4;e++) {
        int o = 4*q + e;
        float gg = ann * ((o & 1) ? vacc[o>>1].y : vacc[o>>1].x);
        o1own[o] = xe[e] + (gg > 0.f ? gg : 0.f);
      }
    }
  }
  // assemble full o1 row from mate, then dense projection (own o-half)
  float o1full[64];
#pragma unroll
  for (int q=0;q<32;q++) {
    float oth = __shfl_xor(o1own[q], 32);
    o1full[col0 + q] = o1own[q];
    o1full[32*(1-g) + q] = oth;
  }
  float ddown[32];
  {
    v2f dacc[16];
#pragma unroll
    for (int j=0;j<16;j++) { v2f t; t.x = bd[col0+2*j]; t.y = bd[col0+2*j+1]; dacc[j] = t; }
    for (int i=0;i<64;i++) {
      v2f xv; xv.x = o1full[i]; xv.y = o1full[i];
      const float4* wr = (const float4*)(Wd + i*64 + col0);
#pragma unroll
      for (int qq=0;qq<8;qq++) {
        float4 w4 = wr[qq];
        v2f wlo; wlo.x=w4.x; wlo.y=w4.y;
        v2f whi; whi.x=w4.z; whi.y=w4.w;
        dacc[2*qq]   = pkfma(xv, wlo, dacc[2*qq]);
        dacc[2*qq+1] = pkfma(xv, whi, dacc[2*qq+1]);
      }
    }
#pragma unroll
    for (int o=0;o<32;o++) ddown[o] = (o & 1) ? dacc[o>>1].y : dacc[o>>1].x;
  }
  float nrm = 0.f;
#pragma unroll
  for (int o=0;o<32;o++) nrm = fmaxf(nrm, fabsf(ddown[o]));
  nrm = fmaxf(nrm, __shfl_xor(nrm, 32));
  __syncthreads();                   // all score/proj reads of ks done before overwrite
#pragma unroll
  for (int q=0;q<8;q++) {
    float4 wv4;
    wv4.x = 0.5f*(ddown[q*4+0]/nrm + 1.f);
    wv4.y = 0.5f*(ddown[q*4+1]/nrm + 1.f);
    wv4.z = 0.5f*(ddown[q*4+2]/nrm + 1.f);
    wv4.w = 0.5f*(ddown[q*4+3]/nrm + 1.f);
    *(float4*)&ks[n*68 + col0 + q*4] = wv4;
  }
  __syncthreads();
  float4* ob4 = (float4*)(vout + (size_t)bt*SLICE);
#pragma unroll
  for (int it=0;it<8;it++) {         // coalesced stage-out (512 threads)
    int flat4 = it*512 + tid;
    int nn = flat4 >> 4, f4 = (flat4 & 15) << 2;
    ob4[flat4] = *(const float4*)&ks[nn*68 + f4];
  }
}

// ---------------- radix-select histograms (values are non-negative floats) ----------------
template<int LEVEL>
__global__ __launch_bounds__(256) void hist_kernel(
    const float* __restrict__ v, unsigned* __restrict__ ghist,
    const unsigned* __restrict__ pfx)
{
  __shared__ unsigned h[4096];
  const int batch = blockIdx.x >> 5, chunk = blockIdx.x & 31;
  const int tid = threadIdx.x;
#pragma unroll
  for (int k=0;k<16;k++) h[k*256+tid] = 0u;
  __syncthreads();
  const unsigned p = pfx ? pfx[batch] : 0u;
  const float4* vb = (const float4*)(v + (size_t)batch*(TT*SLICE)) + chunk*8192 + tid;
  for (int k=0;k<32;k++) {
    float4 q = vb[k*256];
    float e[4] = {q.x,q.y,q.z,q.w};
#pragma unroll
    for (int j=0;j<4;j++) {
      unsigned u = __float_as_uint(e[j]);
      if (LEVEL==1) atomicAdd(&h[u>>20], 1u);
      else if ((u>>20)==p) atomicAdd(&h[(u>>8)&0xFFFu], 1u);
    }
  }
  __syncthreads();
  unsigned* gh = ghist + batch*4096;
#pragma unroll
  for (int k=0;k<16;k++) { unsigned c = h[k*256+tid]; if (c) atomicAdd(&gh[k*256+tid], c); }
}

__global__ __launch_bounds__(256) void hist8_kernel(
    const float* __restrict__ v, unsigned* __restrict__ ghist,
    const unsigned* __restrict__ pfx)
{
  __shared__ unsigned h[256];
  const int batch = blockIdx.x >> 5, chunk = blockIdx.x & 31;
  const int tid = threadIdx.x;
  h[tid] = 0u;
  __syncthreads();
  const unsigned p = pfx[batch];
  const float4* vb = (const float4*)(v + (size_t)batch*(TT*SLICE)) + chunk*8192 + tid;
  for (int k=0;k<32;k++) {
    float4 q = vb[k*256];
    float e[4] = {q.x,q.y,q.z,q.w};
#pragma unroll
    for (int j=0;j<4;j++) {
      unsigned u = __float_as_uint(e[j]);
      if ((u>>8)==p) atomicAdd(&h[u & 255u], 1u);
    }
  }
  __syncthreads();
  unsigned c = h[tid];
  if (c) atomicAdd(&ghist[batch*256+tid], c);
}

// ---------------- find bin containing the rank (block scan per batch) ----------------
template<int PER>
__global__ __launch_bounds__(256) void find_kernel(
    const unsigned* __restrict__ hist,
    const unsigned* __restrict__ rank_in, const unsigned* __restrict__ pfx_in,
    int pfx_shift, unsigned* __restrict__ pfx_out, unsigned* __restrict__ rank_out,
    float* __restrict__ mu, int final_level)
{
  __shared__ unsigned csum[256];
  const int batch = blockIdx.x;
  const int tid = threadIdx.x;
  const unsigned* hb = hist + batch*(PER*256);
  unsigned loc[PER];
  unsigned s = 0;
#pragma unroll
  for (int q=0;q<PER;q++) { loc[q] = hb[tid*PER+q]; s += loc[q]; }
  csum[tid] = s;
  __syncthreads();
  for (int off=1; off<256; off<<=1) {   // inclusive Hillis-Steele scan
    unsigned vv = csum[tid];
    unsigned ad = (tid >= off) ? csum[tid-off] : 0u;
    __syncthreads();
    csum[tid] = vv + ad;
    __syncthreads();
  }
  const unsigned rank = rank_in ? rank_in[batch] : RANK0;
  const unsigned excl = csum[tid] - s;
  if (rank >= excl && rank < excl + s) {
    unsigned r = rank - excl;
    int bin = 0;
#pragma unroll
    for (int q=0;q<PER;q++) {
      if (r < loc[q]) { bin = tid*PER + q; break; }
      r -= loc[q];
    }
    unsigned pf = pfx_in ? pfx_in[batch] : 0u;
    unsigned np = (pf << pfx_shift) | (unsigned)bin;
    if (final_level) { mu[batch] = __uint_as_float(np); }
    else { pfx_out[batch] = np; rank_out[batch] = r; }
  }
}

// ---------------- sigmoid + STE mask + predictor, per (b,t) ----------------
__global__ __launch_bounds__(256,2) void final_kernel(
    const float* __restrict__ v, const float* __restrict__ mu,
    const float* __restrict__ Wp, const float* __restrict__ bp,
    float* __restrict__ pred, float* __restrict__ mask)
{
  __shared__ float sl[NNODES*68];
  const int bt = blockIdx.x;
  const int b = bt >> 6;
  const int tid = threadIdx.x;
  const float4* vb4 = (const float4*)(v + (size_t)bt*SLICE);
#pragma unroll
  for (int it=0; it<16; it++) {
    int flat4 = it*256 + tid;
    int n = flat4 >> 4, f4 = (flat4 & 15) << 2;
    *(float4*)&sl[n*68 + f4] = vb4[flat4];
  }
  __syncthreads();
  const float muv = mu[b];
  float srow[64];                    // masked = s*mask row kept in registers
#pragma unroll
  for (int q=0;q<16;q++) {
    float4 vv = *(const float4*)&sl[tid*68 + q*4];
    float e0 = 1.f/(1.f + expf(-(vv.x - muv)));
    float e1 = 1.f/(1.f + expf(-(vv.y - muv)));
    float e2 = 1.f/(1.f + expf(-(vv.z - muv)));
    float e3 = 1.f/(1.f + expf(-(vv.w - muv)));
    float m0 = rintf(e0), m1 = rintf(e1), m2 = rintf(e2), m3 = rintf(e3);  // round half-even
    srow[q*4+0] = e0*m0; srow[q*4+1] = e1*m1; srow[q*4+2] = e2*m2; srow[q*4+3] = e3*m3;
    float4 w; w.x=m0; w.y=m1; w.z=m2; w.w=m3;
    *(float4*)&sl[tid*68 + q*4] = w;  // own row only: safe
  }
  __syncthreads();
  float4* mb4 = (float4*)(mask + (size_t)bt*SLICE);
#pragma unroll
  for (int it=0; it<16; it++) {
    int flat4 = it*256 + tid;
    int n = flat4 >> 4, f4 = (flat4 & 15) << 2;
    mb4[flat4] = *(const float4*)&sl[n*68 + f4];
  }
  // predictor row
  float acc[64];
#pragma unroll
  for (int o=0;o<64;o++) acc[o]=0.f;
  for (int i=0;i<64;i++) {
    float sv = srow[i];
#pragma unroll
    for (int o=0;o<64;o++) acc[o] = fmaf(sv, Wp[i*64+o], acc[o]);
  }
  __syncthreads();                   // mask stage-out finished reading sl
#pragma unroll
  for (int q=0;q<16;q++) {
    float4 w;
    w.x = acc[q*4+0]+bp[q*4+0]; w.y = acc[q*4+1]+bp[q*4+1];
    w.z = acc[q*4+2]+bp[q*4+2]; w.w = acc[q*4+3]+bp[q*4+3];
    *(float4*)&sl[tid*68 + q*4] = w;
  }
  __syncthreads();
  float4* pb4 = (float4*)(pred + (size_t)bt*SLICE);
#pragma unroll
  for (int it=0; it<16; it++) {
    int flat4 = it*256 + tid;
    int n = flat4 >> 4, f4 = (flat4 & 15) << 2;
    pb4[flat4] = *(const float4*)&sl[n*68 + f4];
  }
}

extern "C" void kernel_launch(void* const* d_in, const int* in_sizes, int n_in,
                              void* d_out, int out_size, void* d_ws, size_t ws_size,
                              hipStream_t stream) {
  const float* x   = (const float*)d_in[0];
  const float* Wc1 = (const float*)d_in[1];  const float* bc1 = (const float*)d_in[2];
  const float* Wc2 = (const float*)d_in[3];  const float* bc2 = (const float*)d_in[4];
  const float* Wc3 = (const float*)d_in[5];  const float* bc3 = (const float*)d_in[6];
  const float* Wq  = (const float*)d_in[7];  const float* bq  = (const float*)d_in[8];
  const float* Wk  = (const float*)d_in[9];
  const float* Wv  = (const float*)d_in[11]; const float* bv  = (const float*)d_in[12];
  const float* Wd  = (const float*)d_in[13]; const float* bd  = (const float*)d_in[14];
  const float* Wp  = (const float*)d_in[15]; const float* bp  = (const float*)d_in[16];

  float* pred = (float*)d_out;       // also holds pre-sigmoid v, overwritten in place
  float* mask = pred + NTOT;         // also holds conv output x1, overwritten in place

  unsigned* hist1 = (unsigned*)d_ws;           // 32*4096
  unsigned* hist2 = hist1 + 32*4096;           // 32*4096
  unsigned* hist3 = hist2 + 32*4096;           // 32*256
  unsigned* pfx1  = hist3 + 32*256;
  unsigned* rank1 = pfx1 + 32;
  unsigned* pfx2  = rank1 + 32;
  unsigned* rank2 = pfx2 + 32;
  float*    muv   = (float*)(rank2 + 32);
  float*    Wcomb = muv + 32;                  // 7*64*64
  float*    bcomb = Wcomb + 7*64*64;           // 64
  float*    Wqk   = bcomb + 64;                // 64*64
  float*    zbv   = Wqk + 64*64;               // 64

  hipMemsetAsync(d_ws, 0, (size_t)(32*4096*2 + 32*256)*sizeof(unsigned), stream);
  combine_w<<<112, 256, 0, stream>>>(Wc1,bc1,Wc2,bc2,Wc3,bc3,Wcomb,bcomb);
  combine_qk<<<17, 256, 0, stream>>>(Wq,bq,Wk,Wqk,zbv);
  conv_kernel<<<BB*NNODES, 256, 0, stream>>>(x, Wcomb, bcomb, mask /*x1*/);
  attn_kernel<<<BB*TT, 512, 0, stream>>>(mask /*x1*/, Wqk,zbv, Wv,bv,Wd,bd, pred /*v*/);
  hist_kernel<1><<<1024, 256, 0, stream>>>(pred, hist1, nullptr);
  find_kernel<16><<<32, 256, 0, stream>>>(hist1, nullptr, nullptr, 0, pfx1, rank1, nullptr, 0);
  hist_kernel<2><<<1024, 256, 0, stream>>>(pred, hist2, pfx1);
  find_kernel<16><<<32, 256, 0, stream>>>(hist2, rank1, pfx1, 12, pfx2, rank2, nullptr, 0);
  hist8_kernel<<<1024, 256, 0, stream>>>(pred, hist3, pfx2);
  find_kernel<1><<<32, 256, 0, stream>>>(hist3, rank2, pfx2, 8, nullptr, nullptr, muv, 1);
  final_kernel<<<BB*TT, 256, 0, stream>>>(pred /*v*/, muv, Wp, bp, pred, mask);
}